// Round 2
// baseline (2796.124 us; speedup 1.0000x reference)
//
#include <hip/hip_runtime.h>

// Problem dims
constexpr int NB = 64;     // batch
constexpr int NI = 2048;   // input capsules
constexpr int NQ = 16;     // input dim
constexpr int NJ = 32;     // num capsules
constexpr int NP = 32;     // dim capsule
constexpr int BC = 8;      // batches per block
constexpr int CI = 16;     // i's per block
constexpr int NIB = NI / CI;        // 128 i-chunks
constexpr int NBB = NB / BC;        // 8 b-chunks
constexpr int NBLK = NIB * NBB;     // 1024 blocks (4/CU, all co-resident)
constexpr int VSZ = NB * NJ * NP;   // 65536 elems per v-buffer

// Fused routing pass. Each thread owns one (j, 4-p-group) and 8 batches.
// W read direct global->register (each W element consumed by exactly 1 thread
// per b-chunk; XCD-swizzled blockIdx makes the 8 b-chunks share one XCD's L2).
// MODE 0: acc[b,j,p] += sum_q x[b,i,q] W[j,i,p,q]   (uniform c folded later)
// MODE 1: per (b,i): hat = x*W ; logit = sum_p S*hat ; c = softmax_j ; acc += c*hat
template <int MODE>
__global__ __launch_bounds__(256, 4)
void fused_pass(const float* __restrict__ X, const float* __restrict__ Wg,
                const float* __restrict__ S, float* __restrict__ ACC)
{
    __shared__ float Sl[BC][NJ][NP];   // 32 KB, p-group XOR-swizzled by j
    __shared__ float xl[2][BC][NQ];    // 1 KB, double-buffered x slice
    __shared__ float red[BC][NJ][4];   // cross-wave p-partials
    __shared__ float cl[BC][NJ];       // softmax coefficients

    const int t  = threadIdx.x;
    const int l  = t & 63;
    const int w  = t >> 6;
    const int j  = l & 31;
    const int ph = l >> 5;
    const int pbase = w * 8 + ph * 4;        // this thread's 4 consecutive p
    const int swz   = (j & 7) << 2;          // Sl bank-spread XOR

    // block decode: XCD r = bid%8 owns ichunks [r*16, r*16+16); all 8 b-chunks
    // of an ichunk get the same r -> same XCD L2 caches that W slice once.
    const int bid = blockIdx.x;
    const int r = bid & 7, s = bid >> 3;
    const int ichunk = r * (NIB / 8) + (s >> 3);
    const int bchunk = s & 7;
    const int i0  = ichunk * CI;
    const int bc0 = bchunk * BC;

    if (MODE == 1) {
        // stage S slice [8][32][32] swizzled (32 KB)
#pragma unroll
        for (int c = 0; c < 8; ++c) {
            const int flat = c * 1024 + t * 4;
            const int k = flat >> 10, rem = flat & 1023;
            const int jj = rem >> 5, p4 = rem & 31;
            const float4 v = *reinterpret_cast<const float4*>(
                S + (size_t)(bc0 + k) * (NJ * NP) + jj * NP + p4);
            *reinterpret_cast<float4*>(&Sl[k][jj][p4 ^ ((jj & 7) << 2)]) = v;
        }
    }
    if (t < BC * NQ) {   // stage x for ii=0
        const int k = t >> 4, q = t & 15;
        xl[0][k][q] = X[((size_t)(bc0 + k) * NI + i0) * NQ + q];
    }

    float acc[BC][4];
#pragma unroll
    for (int k = 0; k < BC; ++k)
#pragma unroll
        for (int pp = 0; pp < 4; ++pp) acc[k][pp] = 0.f;

    // per-thread W base: W[j, i, pbase..pbase+3, 0..15] is 256 B contiguous
    const float* Wt = Wg + (size_t)j * NI * (NP * NQ) + (size_t)pbase * NQ;

    __syncthreads();

#pragma unroll 1
    for (int ii = 0; ii < CI; ++ii) {
        const int i = i0 + ii;

        // stage next x slice (other buffer; barrier at loop end covers hazards)
        if (ii + 1 < CI && t < BC * NQ) {
            const int k = t >> 4, q = t & 15;
            xl[(ii + 1) & 1][k][q] = X[((size_t)(bc0 + k) * NI + (i + 1)) * NQ + q];
        }

        const float* Wi = Wt + (size_t)i * (NP * NQ);
        float hat[BC][4];
#pragma unroll
        for (int k = 0; k < BC; ++k)
#pragma unroll
            for (int pp = 0; pp < 4; ++pp) hat[k][pp] = 0.f;

#pragma unroll
        for (int qb = 0; qb < 4; ++qb) {
            float4 wv[4];
#pragma unroll
            for (int pp = 0; pp < 4; ++pp)
                wv[pp] = *reinterpret_cast<const float4*>(Wi + pp * NQ + qb * 4);
#pragma unroll
            for (int k = 0; k < BC; ++k) {
                const float4 x4 = *reinterpret_cast<const float4*>(&xl[ii & 1][k][qb * 4]);
#pragma unroll
                for (int pp = 0; pp < 4; ++pp) {
                    hat[k][pp] += x4.x * wv[pp].x + x4.y * wv[pp].y +
                                  x4.z * wv[pp].z + x4.w * wv[pp].w;
                }
            }
        }

        if (MODE == 0) {
#pragma unroll
            for (int k = 0; k < BC; ++k)
#pragma unroll
                for (int pp = 0; pp < 4; ++pp) acc[k][pp] += hat[k][pp];
            __syncthreads();   // xl double-buffer hazard
        } else {
            // logits: lane partial over its 4 p, fold p-half via shfl, stash per wave
#pragma unroll
            for (int k = 0; k < BC; ++k) {
                const float4 sk = *reinterpret_cast<const float4*>(&Sl[k][j][pbase ^ swz]);
                float part = sk.x * hat[k][0] + sk.y * hat[k][1] +
                             sk.z * hat[k][2] + sk.w * hat[k][3];
                part += __shfl_xor(part, 32);
                if (ph == 0) red[k][j][w] = part;
            }
            __syncthreads();

            // reduce 4 wave-partials + softmax over j (one thread per (k,j))
            {
                const int k = t >> 5, jr = t & 31;
                const float4 r4 = *reinterpret_cast<const float4*>(&red[k][jr][0]);
                const float bsum = r4.x + r4.y + r4.z + r4.w;
                float m = bsum;
#pragma unroll
                for (int d = 1; d < 32; d <<= 1) m = fmaxf(m, __shfl_xor(m, d));
                const float e = __expf(bsum - m);
                float ssum = e;
#pragma unroll
                for (int d = 1; d < 32; d <<= 1) ssum += __shfl_xor(ssum, d);
                cl[k][jr] = e / ssum;
            }
            __syncthreads();

            // weighted accumulate
#pragma unroll
            for (int k = 0; k < BC; ++k) {
                const float c = cl[k][j];
#pragma unroll
                for (int pp = 0; pp < 4; ++pp) acc[k][pp] += c * hat[k][pp];
            }
            __syncthreads();   // cl/red/xl hazards
        }
    }

    // flush block partials
#pragma unroll
    for (int k = 0; k < BC; ++k)
#pragma unroll
        for (int pp = 0; pp < 4; ++pp)
            atomicAdd(&ACC[(size_t)(bc0 + k) * (NJ * NP) + j * NP + pbase + pp],
                      acc[k][pp]);
}

// v = squash(U*scale) (+ ADD)   ; squash over last axis (P=32)
__global__ __launch_bounds__(256)
void squash_kernel(const float* __restrict__ U, const float* __restrict__ ADD,
                   float* __restrict__ OUT, float scale)
{
    const int t   = threadIdx.x;
    const int row = blockIdx.x * 8 + (t >> 5);   // (b*J + j)
    const int p   = t & 31;
    const float val = U[row * 32 + p] * scale;
    float sq = val * val;
#pragma unroll
    for (int d = 1; d < 32; d <<= 1) sq += __shfl_xor(sq, d);
    const float sc = sq / ((1.f + sq) * sqrtf(sq + 1e-7f));
    float o = val * sc;
    if (ADD != nullptr) o += ADD[row * 32 + p];
    OUT[row * 32 + p] = o;
}

extern "C" void kernel_launch(void* const* d_in, const int* in_sizes, int n_in,
                              void* d_out, int out_size, void* d_ws, size_t ws_size,
                              hipStream_t stream)
{
    const float* X  = (const float*)d_in[0];   // [64, 2048, 16]
    const float* Wg = (const float*)d_in[1];   // [32, 2048, 32, 16]
    float* out = (float*)d_out;                // [64, 32, 32]

    float* v1u = (float*)d_ws;
    float* v1  = v1u + VSZ;
    float* v2u = v1  + VSZ;
    float* sb  = v2u + VSZ;
    float* ou  = sb  + VSZ;

    hipMemsetAsync(d_ws, 0, (size_t)5 * VSZ * sizeof(float), stream);

    const dim3 grid(NBLK), blk(256);

    // iter 1: c = 1/32 uniform
    fused_pass<0><<<grid, blk, 0, stream>>>(X, Wg, nullptr, v1u);
    squash_kernel<<<VSZ / (32 * 8), 256, 0, stream>>>(v1u, nullptr, v1, 1.f / 32.f);

    // iter 2: b1 = sum_p v1*hat
    fused_pass<1><<<grid, blk, 0, stream>>>(X, Wg, v1, v2u);
    squash_kernel<<<VSZ / (32 * 8), 256, 0, stream>>>(v2u, v1, sb, 1.f);  // sb = v1+v2

    // final: b2 = sum_p (v1+v2)*hat
    fused_pass<1><<<grid, blk, 0, stream>>>(X, Wg, sb, ou);
    squash_kernel<<<VSZ / (32 * 8), 256, 0, stream>>>(ou, nullptr, out, 1.f);
}

// Round 3
// 217.846 us; speedup vs baseline: 12.8353x; 12.8353x over previous
//
#include <hip/hip_runtime.h>

typedef _Float16 h8 __attribute__((ext_vector_type(8)));
typedef _Float16 h4 __attribute__((ext_vector_type(4)));
typedef float f4 __attribute__((ext_vector_type(4)));

constexpr int NB = 64;     // batch
constexpr int NI = 2048;   // input capsules
constexpr int NQ = 16;     // input dim
constexpr int NJ = 32;     // num capsules
constexpr int NP = 32;     // dim capsule
constexpr int VSZ = NB * NJ * NP;   // 65536 per v-buffer

// ---------------------------------------------------------------------------
// MFMA plan, per (j,i) task:  D[p(32), b(64)] = sum_q W[j,i,p,q] * x[b,i,q]
//   v_mfma_f32_16x16x32_f16, A = W-side [M=p16, K=32], B = x-side [K=32, N=b16]
//   K slots: k<16 -> (W_hi[q=k], x[q=k]) ; k>=16 -> (W_lo[q=k-16], x[q=k-16])
//   => D = sum_q (W_hi + W_lo) * x   : W at ~f32 precision, x at f16 (2^-11)
//   A lane layout: row p = l&15 (+16 per pfrag), k = (l>>4)*8+e
//   B lane layout: col b = l&15 (+16 per bfrag), k = (l>>4)*8+e  (halves dup'd)
//   D lane layout: col b = l&15, row p = (l>>4)*4 + reg (+16 per pfrag)
// ---------------------------------------------------------------------------

// x fragment prepack: xp[(i*4+bf)*64 + lane] = 8 f16 of x[b=(l&15)+16bf, i, q0..q0+7]
// with q0 = ((l>>4)&1)*8  (upper k-half duplicates lower -> same q pattern)
__global__ __launch_bounds__(256)
void xpack_kernel(const float* __restrict__ X, h8* __restrict__ xp)
{
    const int i = blockIdx.x;
    const int t = threadIdx.x;
    const int bf = t >> 6, l = t & 63;
    const int b = (l & 15) + 16 * bf;
    const int q0 = ((l >> 4) & 1) * 8;
    const float* xs = X + ((size_t)b * NI + i) * NQ + q0;
    const float4 u = *reinterpret_cast<const float4*>(xs);
    const float4 v = *reinterpret_cast<const float4*>(xs + 4);
    h8 h;
    h[0] = (_Float16)u.x; h[1] = (_Float16)u.y; h[2] = (_Float16)u.z; h[3] = (_Float16)u.w;
    h[4] = (_Float16)v.x; h[5] = (_Float16)v.y; h[6] = (_Float16)v.z; h[7] = (_Float16)v.w;
    xp[(size_t)(i * 4 + bf) * 64 + l] = h;
}

// Build one A fragment: 8 f32 W values -> f16 hi (lanes 0..31) or f16 residual (lanes 32..63)
__device__ inline h8 buildA(const float* __restrict__ wp, bool lo)
{
    const float4 u = *reinterpret_cast<const float4*>(wp);
    const float4 v = *reinterpret_cast<const float4*>(wp + 4);
    float wv_[8] = {u.x, u.y, u.z, u.w, v.x, v.y, v.z, v.w};
    h8 a;
#pragma unroll
    for (int e = 0; e < 8; ++e) {
        const float w = wv_[e];
        const _Float16 hi = (_Float16)w;
        const float r = w - (float)hi;
        a[e] = lo ? (_Float16)r : hi;
    }
    return a;
}

// K1: logits + softmax -> routing coefficients c (f16)
// block = one i-chunk of 8, all 32 j, all 64 b. 8 waves; wave wv owns j = wv*4..wv*4+3.
__global__ __launch_bounds__(512)
void logits_kernel(const float* __restrict__ Wg, const h8* __restrict__ xp,
                   const float* __restrict__ S, _Float16* __restrict__ cp)
{
    __shared__ float L[8][32][64];   // 64 KB logits
    const int t = threadIdx.x, wv = t >> 6, l = t & 63;
    const int i0 = blockIdx.x * 8;
    const bool lo = l >= 32;
    const int q0 = ((l >> 4) & 1) * 8;

#pragma unroll 1
    for (int jj = 0; jj < 4; ++jj) {
        const int j = wv * 4 + jj;
        // hoist S[b, j, p] for this wave's D layout (constant over i)
        float sreg[4][8];
#pragma unroll
        for (int bf = 0; bf < 4; ++bf) {
            const int b = (l & 15) + 16 * bf;
#pragma unroll
            for (int pf = 0; pf < 2; ++pf) {
                const float4 sv = *reinterpret_cast<const float4*>(
                    S + ((size_t)b * NJ + j) * NP + (l >> 4) * 4 + 16 * pf);
                sreg[bf][pf * 4 + 0] = sv.x; sreg[bf][pf * 4 + 1] = sv.y;
                sreg[bf][pf * 4 + 2] = sv.z; sreg[bf][pf * 4 + 3] = sv.w;
            }
        }
#pragma unroll 1
        for (int ii = 0; ii < 8; ++ii) {
            const int i = i0 + ii;
            const float* wbase = Wg + ((size_t)j * NI + i) * (NP * NQ) + q0;
            const h8 A0 = buildA(wbase + (size_t)(l & 15) * NQ, lo);
            const h8 A1 = buildA(wbase + (size_t)((l & 15) + 16) * NQ, lo);
            const h8* xpb = xp + (size_t)i * 4 * 64;
            f4 D[2][4];
#pragma unroll
            for (int pf = 0; pf < 2; ++pf)
#pragma unroll
                for (int bf = 0; bf < 4; ++bf) { f4 Z = {0.f, 0.f, 0.f, 0.f}; D[pf][bf] = Z; }
#pragma unroll
            for (int bf = 0; bf < 4; ++bf) {
                const h8 B = xpb[bf * 64 + l];
                D[0][bf] = __builtin_amdgcn_mfma_f32_16x16x32_f16(A0, B, D[0][bf], 0, 0, 0);
                D[1][bf] = __builtin_amdgcn_mfma_f32_16x16x32_f16(A1, B, D[1][bf], 0, 0, 0);
            }
            // logit[b] = sum_p S[b,j,p] * hat[p,b]
            float part[4];
#pragma unroll
            for (int bf = 0; bf < 4; ++bf) {
                float p_ = 0.f;
#pragma unroll
                for (int pf = 0; pf < 2; ++pf)
#pragma unroll
                    for (int r = 0; r < 4; ++r) p_ += sreg[bf][pf * 4 + r] * D[pf][bf][r];
                p_ += __shfl_xor(p_, 16);
                p_ += __shfl_xor(p_, 32);
                part[bf] = p_;
            }
            const int hb = l >> 4;
            const float wval = hb == 0 ? part[0] : hb == 1 ? part[1] : hb == 2 ? part[2] : part[3];
            L[ii][j][(l & 15) + 16 * hb] = wval;
        }
    }
    __syncthreads();

    // softmax over j, one thread per (b, ii); write c in K2's B-frag order
    {
        const int b = t & 63, ii = t >> 6;
        const int i = i0 + ii;
        float lv[32];
        float m = -1e30f;
#pragma unroll
        for (int j = 0; j < 32; ++j) { lv[j] = L[ii][j][b]; m = fmaxf(m, lv[j]); }
        float s = 0.f;
#pragma unroll
        for (int j = 0; j < 32; ++j) { lv[j] = __expf(lv[j] - m); s += lv[j]; }
        const float inv = 1.f / s;
#pragma unroll
        for (int j = 0; j < 32; ++j)
            cp[((size_t)j * NI + i) * 64 + (b & 15) * 4 + (b >> 4)] = (_Float16)(lv[j] * inv);
    }
}

// K2: ACC[b,j,p] += sum_i c[b,j,i] * hat[b,j,i,p]   (c==nullptr -> uniform, scaled later)
// block = (j, i-stripe of 256); wave wv accumulates its 32 i's fully in D regs.
template <bool HASC>
__global__ __launch_bounds__(512)
void accum_kernel(const float* __restrict__ Wg, const h8* __restrict__ xp,
                  const _Float16* __restrict__ cp, float* __restrict__ ACC)
{
    const int t = threadIdx.x, wv = t >> 6, l = t & 63;
    const int j = blockIdx.x >> 3, is = blockIdx.x & 7;
    const bool lo = l >= 32;
    const int q0 = ((l >> 4) & 1) * 8;

    f4 D[2][4];
#pragma unroll
    for (int pf = 0; pf < 2; ++pf)
#pragma unroll
        for (int bf = 0; bf < 4; ++bf) { f4 Z = {0.f, 0.f, 0.f, 0.f}; D[pf][bf] = Z; }

    const int ibase = is * 256 + wv * 32;
#pragma unroll 1
    for (int ii = 0; ii < 32; ++ii) {
        const int i = ibase + ii;
        const float* wbase = Wg + ((size_t)j * NI + i) * (NP * NQ) + q0;
        const h8 A0 = buildA(wbase + (size_t)(l & 15) * NQ, lo);
        const h8 A1 = buildA(wbase + (size_t)((l & 15) + 16) * NQ, lo);
        const h8* xpb = xp + (size_t)i * 4 * 64;
        h4 c4;
        if (HASC)
            c4 = *reinterpret_cast<const h4*>(cp + ((size_t)j * NI + i) * 64 + (l & 15) * 4);
#pragma unroll
        for (int bf = 0; bf < 4; ++bf) {
            h8 B = xpb[bf * 64 + l];
            if (HASC) B = B * c4[bf];   // fold c into B operand (v_pk_mul_f16)
            D[0][bf] = __builtin_amdgcn_mfma_f32_16x16x32_f16(A0, B, D[0][bf], 0, 0, 0);
            D[1][bf] = __builtin_amdgcn_mfma_f32_16x16x32_f16(A1, B, D[1][bf], 0, 0, 0);
        }
    }

    // cross-wave reduce in LDS, then one atomic per (b,p)
    __shared__ float R[8][64 * 36];   // stride 36 keeps float4 stores 16B-aligned
#pragma unroll
    for (int pf = 0; pf < 2; ++pf)
#pragma unroll
        for (int bf = 0; bf < 4; ++bf) {
            const int b = (l & 15) + 16 * bf, p = (l >> 4) * 4 + 16 * pf;
            *reinterpret_cast<f4*>(&R[wv][b * 36 + p]) = D[pf][bf];
        }
    __syncthreads();
#pragma unroll
    for (int k = 0; k < 4; ++k) {
        const int id = t + k * 512;
        const int b = id >> 5, p = id & 31;
        float s = 0.f;
#pragma unroll
        for (int w8 = 0; w8 < 8; ++w8) s += R[w8][b * 36 + p];
        atomicAdd(ACC + ((size_t)b * NJ + j) * NP + p, s);
    }
}

// v = squash(U*scale) (+ ADD) over last axis (P=32)
__global__ __launch_bounds__(256)
void squash_kernel(const float* __restrict__ U, const float* __restrict__ ADD,
                   float* __restrict__ OUT, float scale)
{
    const int t   = threadIdx.x;
    const int row = blockIdx.x * 8 + (t >> 5);
    const int p   = t & 31;
    const float val = U[row * 32 + p] * scale;
    float sq = val * val;
#pragma unroll
    for (int d = 1; d < 32; d <<= 1) sq += __shfl_xor(sq, d);
    const float sc = sq / ((1.f + sq) * sqrtf(sq + 1e-7f));
    float o = val * sc;
    if (ADD != nullptr) o += ADD[row * 32 + p];
    OUT[row * 32 + p] = o;
}

extern "C" void kernel_launch(void* const* d_in, const int* in_sizes, int n_in,
                              void* d_out, int out_size, void* d_ws, size_t ws_size,
                              hipStream_t stream)
{
    const float* X  = (const float*)d_in[0];   // [64, 2048, 16]
    const float* Wg = (const float*)d_in[1];   // [32, 2048, 32, 16]
    float* out = (float*)d_out;                // [64, 32, 32]

    // workspace layout
    float* v1u = (float*)d_ws;        // 5 x 256 KB f32 v-buffers
    float* v1  = v1u + VSZ;
    float* v2u = v1  + VSZ;
    float* sb  = v2u + VSZ;
    float* ou  = sb  + VSZ;
    h8* xp = (h8*)((char*)d_ws + (size_t)5 * VSZ * 4);              // 8 MB
    _Float16* cp = (_Float16*)((char*)xp + (size_t)NI * 4 * 64 * 16); // 8 MB

    hipMemsetAsync(d_ws, 0, (size_t)5 * VSZ * sizeof(float), stream);

    xpack_kernel<<<NI, 256, 0, stream>>>(X, xp);

    // pass A: c = 1/32 uniform
    accum_kernel<false><<<256, 512, 0, stream>>>(Wg, xp, nullptr, v1u);
    squash_kernel<<<VSZ / 256, 256, 0, stream>>>(v1u, nullptr, v1, 1.f / 32.f);

    // pass B: logits vs v1
    logits_kernel<<<NI / 8, 512, 0, stream>>>(Wg, xp, v1, cp);
    accum_kernel<true><<<256, 512, 0, stream>>>(Wg, xp, cp, v2u);
    squash_kernel<<<VSZ / 256, 256, 0, stream>>>(v2u, v1, sb, 1.f);   // sb = v1 + v2

    // pass C: logits vs (v1+v2)
    logits_kernel<<<NI / 8, 512, 0, stream>>>(Wg, xp, sb, cp);
    accum_kernel<true><<<256, 512, 0, stream>>>(Wg, xp, cp, ou);
    squash_kernel<<<VSZ / 256, 256, 0, stream>>>(ou, nullptr, out, 1.f);
}